// Round 5
// baseline (103.944 us; speedup 1.0000x reference)
//
#include <hip/hip_runtime.h>
#include <math.h>

// AEV computer (ANI-style): 32 molecules x 48 atoms, 4 species.
// Inputs (contract order): species int32[1536], coordinates f32[1536*3].
// Output: f32[32*48*384]; per atom 64 radial (s*16+t) + 320 angular (p*32+ia*8+iz).
// Robust to input-order permutation (coords = 3x-larger buffer) and to
// coords f32-vs-bf16 / species int32-vs-int64-vs-f32 via device sniffing.

#define A_ATOMS 48
#define NMOL    32
#define NFEAT   384

// cos/sin of SHFZ = (2*iz+1)*pi/16, iz = 0..7
__device__ __constant__ float CZ_TAB[8] = {
     0.980785280f,  0.831469612f,  0.555570233f,  0.195090322f,
    -0.195090322f, -0.555570233f, -0.831469612f, -0.980785280f };
__device__ __constant__ float SZ_TAB[8] = {
     0.195090322f,  0.555570233f,  0.831469612f,  0.980785280f,
     0.980785280f,  0.831469612f,  0.555570233f,  0.195090322f };

__device__ __forceinline__ float bf2f(unsigned short h) {
    return __uint_as_float(((unsigned int)h) << 16);
}

__global__ __launch_bounds__(64)
void AEVComputer_2156073583107_kernel(const void* __restrict__ coords_raw,
                                      const void* __restrict__ species_raw,
                                      float* __restrict__ out)
{
    const int bid  = blockIdx.x;
    const int n    = bid / A_ATOMS;      // molecule
    const int i    = bid - n * A_ATOMS;  // center atom
    const int lane = threadIdx.x;        // one wave of 64

    // ---- dtype sniffs (uniform across lanes/blocks; L2-hot, negligible) ----
    const unsigned short* cu16 = (const unsigned short*)coords_raw;
    int sane = 0;
    for (int k = 0; k < 64; ++k) {
        float v = bf2f(cu16[k]);
        if (fabsf(v) < 32.0f) ++sane;        // NaN compares false -> insane
    }
    const bool coords_bf16 = (sane >= 60);   // f32 data scores ~48, bf16 scores 64

    const unsigned int* su32 = (const unsigned int*)species_raw;
    int f32like = 0;
    bool zero_odd = true;
    for (int k = 0; k < 32; ++k) {
        unsigned int v = su32[k];
        if (v >= 0x3F000000u && v < 0x40800000u) ++f32like;  // 0.5..4.0 as f32 bits
    }
    for (int k = 1; k < 32; k += 2) if (su32[k] != 0u) zero_odd = false;
    const int smode = (f32like > 20) ? 2 : (zero_odd ? 1 : 0); // 2=f32, 1=i64, 0=i32

    __shared__ float cx[A_ATOMS], cy[A_ATOMS], cz[A_ATOMS];
    __shared__ int   sp[A_ATOMS];
    __shared__ float dL[A_ATOMS], fcaL[A_ATOMS];
    __shared__ float ux[A_ATOMS], uy[A_ATOMS], uz[A_ATOMS];
    __shared__ int   nbr[A_ATOMS];
    __shared__ int   Msh;
    __shared__ float ang_acc[640];   // two 320-float halves (sub 0 / sub 1)

    for (int idx = lane; idx < 640; idx += 64) ang_acc[idx] = 0.0f;

    if (lane < A_ATOMS) {
        const int g = n * A_ATOMS + lane;
        float x, y, z;
        if (coords_bf16) {
            x = bf2f(cu16[3 * g + 0]);
            y = bf2f(cu16[3 * g + 1]);
            z = bf2f(cu16[3 * g + 2]);
        } else {
            const float* cf = (const float*)coords_raw;
            x = cf[3 * g + 0];
            y = cf[3 * g + 1];
            z = cf[3 * g + 2];
        }
        cx[lane] = x; cy[lane] = y; cz[lane] = z;
        int sv;
        if (smode == 0)      sv = ((const int*)species_raw)[g];
        else if (smode == 1) sv = ((const int*)species_raw)[2 * g];
        else                 sv = (int)(((const float*)species_raw)[g] + 0.5f);
        sp[lane] = (sv < 0) ? 0 : ((sv > 3) ? 3 : sv);   // clamp: no OOB ever
    }
    __syncthreads();

    // ---- per-j geometry ----
    const float xi = cx[i], yi = cy[i], zi = cz[i];
    if (lane < A_ATOMS) {
        float dx = cx[lane] - xi;
        float dy = cy[lane] - yi;
        float dz = cz[lane] - zi;
        float d2 = dx * dx + dy * dy + dz * dz;
        float d  = (lane == i) ? 1.0f : sqrtf(d2);
        float inv = 1.0f / d;
        dL[lane] = d;
        ux[lane] = dx * inv;
        uy[lane] = dy * inv;
        uz[lane] = dz * inv;
        float fca = 0.0f;
        if (lane != i && d < 3.5f)
            fca = 0.5f * cosf(0.8975979010f * d) + 0.5f;   // pi/3.5
        fcaL[lane] = fca;
    }
    __syncthreads();

    // ---- radial: feature index == lane (s = lane>>4, t = lane&15) ----
    float radv = 0.0f;
    {
        const int   s    = lane >> 4;
        const int   t    = lane & 15;
        const float shfr = 0.9f + 0.26875f * (float)t;
        for (int j = 0; j < A_ATOMS; ++j) {
            if (j == i) continue;
            float d = dL[j];
            if (d < 5.2f && sp[j] == s) {
                float fcr = 0.5f * cosf(0.6041524333f * d) + 0.5f;  // pi/5.2
                float e   = d - shfr;
                radv += 0.25f * expf(-16.0f * e * e) * fcr;
            }
        }
    }

    // ---- neighbor list (angular cutoff), lane-0 serial compaction ----
    if (lane == 0) {
        int m = 0;
        for (int j = 0; j < A_ATOMS; ++j)
            if (j != i && dL[j] < 3.5f) nbr[m++] = j;
        Msh = m;
    }
    __syncthreads();
    const int M = Msh;

    // ---- angular: sub-wave 0 takes even pair offsets, sub 1 odd ----
    {
        const int   sub  = lane >> 5;         // 0 or 1
        const int   t    = lane & 31;         // ia*8 + iz
        const int   ia   = t >> 3;
        const int   iz   = t & 7;
        const float shfa = 0.9f + 0.65f * (float)ia;
        const float czv  = CZ_TAB[iz];
        const float szv  = SZ_TAB[iz];
        float* acc = &ang_acc[sub * 320];

        for (int jj = 0; jj < M - 1; ++jj) {
            const int   j   = nbr[jj];
            const float ujx = ux[j], ujy = uy[j], ujz = uz[j];
            const float dj  = dL[j];
            const float fj  = fcaL[j];
            const int   sj  = sp[j];
            for (int kk = jj + 1 + sub; kk < M; kk += 2) {
                const int k = nbr[kk];
                float c  = ujx * ux[k] + ujy * uy[k] + ujz * uz[k];
                float cc = 0.95f * c;
                float ss = sqrtf(fmaxf(1.0f - cc * cc, 0.0f));
                // cos(acos(cc) - shfz) = cc*cos(shfz) + sqrt(1-cc^2)*sin(shfz)
                float x  = 0.5f * (1.0f + cc * czv + ss * szv);
                float x2 = x * x, x4 = x2 * x2, x8 = x4 * x4, x16 = x8 * x8;
                float f1 = x16 * x16;                       // x^32
                float dm = 0.5f * (dj + dL[k]) - shfa;
                float f2 = expf(-8.0f * dm * dm);
                float term = 2.0f * fj * fcaL[k] * f2 * f1; // x2: unordered pairs
                int sk = sp[k];
                int lo = (sj < sk) ? sj : sk;
                int hi = (sj < sk) ? sk : sj;
                int p  = (lo * (7 - lo)) / 2 + hi;          // TRIU index (verified)
                acc[p * 32 + t] += term;
            }
        }
    }
    __syncthreads();

    // ---- write 384 FLOAT32 features ----
    const size_t base = (size_t)(n * A_ATOMS + i) * NFEAT;
    out[base + lane] = radv;                                // radial: f == lane
    for (int g = lane; g < 320; g += 64)
        out[base + 64 + g] = ang_acc[g] + ang_acc[320 + g];
}

extern "C" void kernel_launch(void* const* d_in, const int* in_sizes, int n_in,
                              void* d_out, int out_size, void* d_ws, size_t ws_size,
                              hipStream_t stream) {
    if (n_in < 2) return;
    // Coordinates buffer has 3x the elements of species; pick by size so input
    // ORDER cannot break us (contract order: species, coordinates).
    const void* coords;
    const void* species;
    if (in_sizes[0] >= in_sizes[1]) { coords = d_in[0]; species = d_in[1]; }
    else                            { coords = d_in[1]; species = d_in[0]; }
    float* out = (float*)d_out;
    AEVComputer_2156073583107_kernel<<<NMOL * A_ATOMS, 64, 0, stream>>>(coords, species, out);
}

// Round 6
// 77.282 us; speedup vs baseline: 1.3450x; 1.3450x over previous
//
#include <hip/hip_runtime.h>
#include <math.h>

// AEV computer (ANI-style): 32 molecules x 48 atoms, 4 species.
// Output: f32[32*48*384]; per atom 64 radial (s*16+t) + 320 angular (p*32+ia*8+iz).
// R6: 256-thread blocks (4 waves/center), register angular accumulators
// (no LDS RMW in inner loop), fast transcendentals.

#define A_ATOMS 48
#define NMOL    32
#define NFEAT   384
#define NW      4      // waves per block
#define NSLICE  8      // wave-halves slicing the pair loop

// cos/sin of SHFZ = (2*iz+1)*pi/16, iz = 0..7
__device__ __constant__ float CZ_TAB[8] = {
     0.980785280f,  0.831469612f,  0.555570233f,  0.195090322f,
    -0.195090322f, -0.555570233f, -0.831469612f, -0.980785280f };
__device__ __constant__ float SZ_TAB[8] = {
     0.195090322f,  0.555570233f,  0.831469612f,  0.980785280f,
     0.980785280f,  0.831469612f,  0.555570233f,  0.195090322f };

__device__ __forceinline__ float bf2f(unsigned short h) {
    return __uint_as_float(((unsigned int)h) << 16);
}

__global__ __launch_bounds__(256)
void AEVComputer_2156073583107_kernel(const void* __restrict__ coords_raw,
                                      const void* __restrict__ species_raw,
                                      float* __restrict__ out)
{
    const int bid  = blockIdx.x;
    const int n    = bid / A_ATOMS;      // molecule
    const int i    = bid - n * A_ATOMS;  // center atom
    const int tid  = threadIdx.x;
    const int w    = tid >> 6;           // wave 0..3
    const int lane = tid & 63;
    const int sub  = lane >> 5;
    const int slice = (w << 1) | sub;    // 0..7

    // ---- dtype sniffs (uniform; L2-hot) ----
    const unsigned short* cu16 = (const unsigned short*)coords_raw;
    int sane = 0;
    for (int k = 0; k < 64; ++k) {
        float v = bf2f(cu16[k]);
        if (fabsf(v) < 32.0f) ++sane;
    }
    const bool coords_bf16 = (sane >= 60);

    const unsigned int* su32 = (const unsigned int*)species_raw;
    int f32like = 0;
    bool zero_odd = true;
    for (int k = 0; k < 32; ++k) {
        unsigned int v = su32[k];
        if (v >= 0x3F000000u && v < 0x40800000u) ++f32like;
    }
    for (int k = 1; k < 32; k += 2) if (su32[k] != 0u) zero_odd = false;
    const int smode = (f32like > 20) ? 2 : (zero_odd ? 1 : 0); // 2=f32, 1=i64, 0=i32

    __shared__ float cx[A_ATOMS], cy[A_ATOMS], cz[A_ATOMS];
    __shared__ int   sp[A_ATOMS];
    __shared__ float dL[A_ATOMS], fcaL[A_ATOMS];
    __shared__ float ux[A_ATOMS], uy[A_ATOMS], uz[A_ATOMS];
    __shared__ int   nbr[A_ATOMS];
    __shared__ int   Msh;
    __shared__ float ang_m[NSLICE][320];
    __shared__ float rad_m[NW][64];

    // ---- stage coords + species ----
    if (tid < A_ATOMS) {
        const int g = n * A_ATOMS + tid;
        float x, y, z;
        if (coords_bf16) {
            x = bf2f(cu16[3 * g + 0]);
            y = bf2f(cu16[3 * g + 1]);
            z = bf2f(cu16[3 * g + 2]);
        } else {
            const float* cf = (const float*)coords_raw;
            x = cf[3 * g + 0]; y = cf[3 * g + 1]; z = cf[3 * g + 2];
        }
        cx[tid] = x; cy[tid] = y; cz[tid] = z;
        int sv;
        if (smode == 0)      sv = ((const int*)species_raw)[g];
        else if (smode == 1) sv = ((const int*)species_raw)[2 * g];
        else                 sv = (int)(((const float*)species_raw)[g] + 0.5f);
        sp[tid] = (sv < 0) ? 0 : ((sv > 3) ? 3 : sv);
    }
    __syncthreads();

    // ---- per-j geometry ----
    if (tid < A_ATOMS) {
        float dx = cx[tid] - cx[i];
        float dy = cy[tid] - cy[i];
        float dz = cz[tid] - cz[i];
        float d2 = dx * dx + dy * dy + dz * dz;
        float d  = (tid == i) ? 1.0f : sqrtf(d2);
        float inv = 1.0f / d;
        dL[tid] = d;
        ux[tid] = dx * inv;
        uy[tid] = dy * inv;
        uz[tid] = dz * inv;
        float fca = 0.0f;
        if (tid != i && d < 3.5f)
            fca = 0.5f * __cosf(0.8975979010f * d) + 0.5f;   // pi/3.5
        fcaL[tid] = fca;
    }
    __syncthreads();

    // ---- neighbor list (wave 0, ballot compaction) ----
    if (tid < 64) {
        bool pred = (tid < A_ATOMS) && (tid != i) && (dL[tid] < 3.5f);
        unsigned long long mask = __ballot(pred);
        if (pred) {
            int pos = __popcll(mask & ((1ull << tid) - 1ull));
            nbr[pos] = tid;
        }
        if (tid == 0) Msh = __popcll(mask);
    }
    __syncthreads();
    const int M = Msh;

    // ---- radial: j strided over waves; feature (s,t) = lane ----
    {
        const int   s    = lane >> 4;
        const int   rt   = lane & 15;
        const float shfr = 0.9f + 0.26875f * (float)rt;
        float radv = 0.0f;
        for (int j = w; j < A_ATOMS; j += NW) {
            if (j == i) continue;
            float d = dL[j];
            if (d < 5.2f && sp[j] == s) {
                float fcr = 0.5f * __cosf(0.6041524333f * d) + 0.5f;  // pi/5.2
                float e   = d - shfr;
                radv += 0.25f * __expf(-16.0f * e * e) * fcr;
            }
        }
        rad_m[w][lane] = radv;
    }

    // ---- angular: pairs strided over 8 slices; register accumulators ----
    {
        const int   t    = lane & 31;        // ia*8 + iz
        const int   ia   = t >> 3;
        const int   iz   = t & 7;
        const float shfa = 0.9f + 0.65f * (float)ia;
        const float czv  = CZ_TAB[iz];
        const float szv  = SZ_TAB[iz];
        float a0=0.f,a1=0.f,a2=0.f,a3=0.f,a4=0.f,a5=0.f,a6=0.f,a7=0.f,a8=0.f,a9=0.f;

        for (int jj = 0; jj < M - 1; ++jj) {
            const int   j   = nbr[jj];
            const float ujx = ux[j], ujy = uy[j], ujz = uz[j];
            const float dj  = dL[j];
            const float fj  = fcaL[j];
            const int   sj  = sp[j];
            for (int kk = jj + 1 + slice; kk < M; kk += NSLICE) {
                const int k = nbr[kk];
                float c  = fmaf(ujx, ux[k], fmaf(ujy, uy[k], ujz * uz[k]));
                float cc = 0.95f * c;
                float ss = sqrtf(fmaxf(1.0f - cc * cc, 0.0f));
                // cos(acos(cc) - shfz) = cc*cos(shfz) + sqrt(1-cc^2)*sin(shfz)
                float x  = 0.5f * (1.0f + fmaf(cc, czv, ss * szv));
                float x2 = x * x, x4 = x2 * x2, x8 = x4 * x4, x16 = x8 * x8;
                float f1 = x16 * x16;                       // x^32
                float dm = fmaf(0.5f, dj + dL[k], -shfa);
                float f2 = __expf(-8.0f * dm * dm);
                float term = 2.0f * fj * fcaL[k] * f2 * f1; // x2: unordered pairs
                const int sk = sp[k];
                // p = TRIU[sj][sk]; sj is wave-uniform -> cheap uniform switch
                switch (sj) {
                  case 0: a0 += (sk==0)?term:0.f; a1 += (sk==1)?term:0.f;
                          a2 += (sk==2)?term:0.f; a3 += (sk==3)?term:0.f; break;
                  case 1: a1 += (sk==0)?term:0.f; a4 += (sk==1)?term:0.f;
                          a5 += (sk==2)?term:0.f; a6 += (sk==3)?term:0.f; break;
                  case 2: a2 += (sk==0)?term:0.f; a5 += (sk==1)?term:0.f;
                          a7 += (sk==2)?term:0.f; a8 += (sk==3)?term:0.f; break;
                  default:a3 += (sk==0)?term:0.f; a6 += (sk==1)?term:0.f;
                          a8 += (sk==2)?term:0.f; a9 += (sk==3)?term:0.f; break;
                }
            }
        }
        // bank = t for every store (stride 320 % 32 == 0): 2 lanes/bank = free
        ang_m[slice][0*32+t] = a0; ang_m[slice][1*32+t] = a1;
        ang_m[slice][2*32+t] = a2; ang_m[slice][3*32+t] = a3;
        ang_m[slice][4*32+t] = a4; ang_m[slice][5*32+t] = a5;
        ang_m[slice][6*32+t] = a6; ang_m[slice][7*32+t] = a7;
        ang_m[slice][8*32+t] = a8; ang_m[slice][9*32+t] = a9;
    }
    __syncthreads();

    // ---- merge + store 384 f32 features ----
    const size_t base = (size_t)bid * NFEAT;
    for (int f = tid; f < NFEAT; f += 256) {
        float v;
        if (f < 64) {
            v = rad_m[0][f] + rad_m[1][f] + rad_m[2][f] + rad_m[3][f];
        } else {
            const int g = f - 64;
            v = ((ang_m[0][g] + ang_m[1][g]) + (ang_m[2][g] + ang_m[3][g]))
              + ((ang_m[4][g] + ang_m[5][g]) + (ang_m[6][g] + ang_m[7][g]));
        }
        out[base + f] = v;
    }
}

extern "C" void kernel_launch(void* const* d_in, const int* in_sizes, int n_in,
                              void* d_out, int out_size, void* d_ws, size_t ws_size,
                              hipStream_t stream) {
    if (n_in < 2) return;
    // Coordinates buffer has 3x the elements of species; pick by size so input
    // ORDER cannot break us.
    const void* coords;
    const void* species;
    if (in_sizes[0] >= in_sizes[1]) { coords = d_in[0]; species = d_in[1]; }
    else                            { coords = d_in[1]; species = d_in[0]; }
    float* out = (float*)d_out;
    AEVComputer_2156073583107_kernel<<<NMOL * A_ATOMS, 256, 0, stream>>>(coords, species, out);
}

// Round 7
// 64.916 us; speedup vs baseline: 1.6012x; 1.1905x over previous
//
#include <hip/hip_runtime.h>
#include <math.h>

// AEV computer (ANI-style): 32 molecules x 48 atoms, 4 species.
// Output: f32[32*48*384]; per atom 64 radial (s*16+t) + 320 angular (p*32+ia*8+iz).
// R7: pair-scalar phase A (1 pair/thread, bucketed by species-pair p) +
// feature-vector phase B (uniform-p inner loop, broadcast b128 reads),
// ballot-based dtype sniffs, wave-0 fused setup.

#define A_ATOMS 48
#define NMOL    32
#define NFEAT   384
#define CHUNK   256

// cos/sin of SHFZ = (2*iz+1)*pi/16, iz = 0..7
__device__ __constant__ float CZ_TAB[8] = {
     0.980785280f,  0.831469612f,  0.555570233f,  0.195090322f,
    -0.195090322f, -0.555570233f, -0.831469612f, -0.980785280f };
__device__ __constant__ float SZ_TAB[8] = {
     0.195090322f,  0.555570233f,  0.831469612f,  0.980785280f,
     0.980785280f,  0.831469612f,  0.555570233f,  0.195090322f };

__device__ __forceinline__ float bf2f(unsigned short h) {
    return __uint_as_float(((unsigned int)h) << 16);
}

__global__ __launch_bounds__(256, 6)
void AEVComputer_2156073583107_kernel(const void* __restrict__ coords_raw,
                                      const void* __restrict__ species_raw,
                                      float* __restrict__ out)
{
    const int bid   = blockIdx.x;
    const int n     = bid / A_ATOMS;      // molecule
    const int i     = bid - n * A_ATOMS;  // center atom
    const int tid   = threadIdx.x;
    const int w     = tid >> 6;           // wave 0..3
    const int lane  = tid & 63;
    const int sub   = lane >> 5;
    const int slice = (w << 1) | sub;     // 0..7
    const int t     = lane & 31;          // feature t = ia*8+iz

    __shared__ float cx[A_ATOMS], cy[A_ATOMS], cz[A_ATOMS];
    __shared__ float dL[A_ATOMS], fcaL[A_ATOMS];
    __shared__ float ux[A_ATOMS], uy[A_ATOMS], uz[A_ATOMS];
    __shared__ int   sp[A_ATOMS], nbr[A_ATOMS];
    __shared__ int   Msh;
    __shared__ float4 pairbuf[CHUNK];
    __shared__ int   cnt[10], curs[10], ofs[11];
    __shared__ float ang_m[8][320];
    __shared__ float rad_m[4][64];

    const unsigned short* cu16 = (const unsigned short*)coords_raw;
    const unsigned int*   su32 = (const unsigned int*)species_raw;

    // ---- wave 0: sniff + stage + geometry + neighbor list (no barriers) ----
    if (tid < 64) {
        // dtype sniffs: one load + ballot each
        float v = bf2f(cu16[tid]);
        unsigned long long mb = __ballot(fabsf(v) < 32.0f);
        const bool coords_bf16 = (__popcll(mb) >= 60);   // f32 scores ~48, bf16 64
        unsigned int sv = su32[tid & 31];
        unsigned long long m2 = __ballot((tid < 32) && sv >= 0x3F000000u && sv < 0x40800000u);
        unsigned long long m3 = __ballot((tid < 32) && (tid & 1) && sv != 0u);
        const int smode = (__popcll(m2) > 20) ? 2 : ((m3 == 0ull) ? 1 : 0);

        if (tid < A_ATOMS) {
            const int g = n * A_ATOMS + tid;
            float x, y, z;
            if (coords_bf16) {
                x = bf2f(cu16[3 * g]); y = bf2f(cu16[3 * g + 1]); z = bf2f(cu16[3 * g + 2]);
            } else {
                const float* cf = (const float*)coords_raw;
                x = cf[3 * g]; y = cf[3 * g + 1]; z = cf[3 * g + 2];
            }
            cx[tid] = x; cy[tid] = y; cz[tid] = z;
            int s;
            if (smode == 0)      s = ((const int*)species_raw)[g];
            else if (smode == 1) s = ((const int*)species_raw)[2 * g];
            else                 s = (int)(((const float*)species_raw)[g] + 0.5f);
            sp[tid] = (s < 0) ? 0 : ((s > 3) ? 3 : s);
        }
        // geometry (same wave: in-order LDS, compiler inserts lgkmcnt)
        if (tid < A_ATOMS) {
            float dx = cx[tid] - cx[i];
            float dy = cy[tid] - cy[i];
            float dz = cz[tid] - cz[i];
            float d2 = dx * dx + dy * dy + dz * dz;
            float d  = (tid == i) ? 1.0f : sqrtf(d2);
            float inv = 1.0f / d;
            dL[tid] = d;
            ux[tid] = dx * inv; uy[tid] = dy * inv; uz[tid] = dz * inv;
            float fca = 0.0f;
            if (tid != i && d < 3.5f)
                fca = 0.5f * __cosf(0.8975979010f * d) + 0.5f;   // pi/3.5
            fcaL[tid] = fca;
        }
        float dv = (tid < A_ATOMS) ? dL[tid] : 1e9f;
        bool pred = (tid < A_ATOMS) && (tid != i) && (dv < 3.5f);
        unsigned long long mask = __ballot(pred);
        if (pred) {
            int pos = __popcll(mask & ((1ull << tid) - 1ull));
            nbr[pos] = tid;
        }
        if (tid == 0) Msh = __popcll(mask);
    }
    __syncthreads();
    const int M = Msh;
    const int npairs = (M * (M - 1)) >> 1;

    // ---- radial: j strided over waves; feature (s,t) = lane ----
    {
        const int   s    = lane >> 4;
        const int   rt   = lane & 15;
        const float shfr = 0.9f + 0.26875f * (float)rt;
        float radv = 0.0f;
        for (int j = w; j < A_ATOMS; j += 4) {
            if (j == i) continue;
            float d = dL[j];
            if (d < 5.2f && sp[j] == s) {
                float fcr = 0.5f * __cosf(0.6041524333f * d) + 0.5f;  // pi/5.2
                float e   = d - shfr;
                radv += 0.25f * __expf(-16.0f * e * e) * fcr;
            }
        }
        rad_m[w][lane] = radv;
    }

    // ---- angular: phase A (pair scalars, bucketed by p) + phase B (features) ----
    float a[10];
    #pragma unroll
    for (int p = 0; p < 10; ++p) a[p] = 0.0f;
    const float czv  = CZ_TAB[t & 7];
    const float szv  = SZ_TAB[t & 7];
    const float shfa = 0.9f + 0.65f * (float)(t >> 3);

    for (int base = 0; base < npairs; base += CHUNK) {
        if (tid < 10) cnt[tid] = 0;
        __syncthreads();

        const int  q     = base + tid;
        const bool havep = (q < npairs);
        float4 pd; int p = 0;
        if (havep) {
            // decode triangular index q -> (jj,kk), jj<kk<M
            const float b = (float)(2 * M - 1);
            int jj = (int)(0.5f * (b - sqrtf(fmaxf(b * b - 8.0f * (float)q, 0.0f))));
            jj = max(0, min(jj, M - 2));
            while (jj > 0 && q < ((jj * (2 * M - 1 - jj)) >> 1)) --jj;
            while (q >= (((jj + 1) * (2 * M - 2 - jj)) >> 1)) ++jj;
            const int kk = jj + 1 + (q - ((jj * (2 * M - 1 - jj)) >> 1));
            const int j = nbr[jj], k = nbr[kk];
            float c  = fmaf(ux[j], ux[k], fmaf(uy[j], uy[k], uz[j] * uz[k]));
            float cc = 0.95f * c;
            float ss = sqrtf(fmaxf(1.0f - cc * cc, 0.0f));
            pd.x = 0.5f * cc;                    // hc
            pd.y = 0.5f * ss;                    // hs
            pd.z = 2.0f * fcaL[j] * fcaL[k];     // w (x2: unordered pairs)
            pd.w = 0.5f * (dL[j] + dL[k]);       // dmean
            int sj = sp[j], sk = sp[k];
            int lo = min(sj, sk), hi = max(sj, sk);
            p = ((lo * (7 - lo)) >> 1) + hi;     // TRIU pair index (verified)
            atomicAdd(&cnt[p], 1);
        }
        __syncthreads();
        if (tid == 0) {
            int o = 0;
            #pragma unroll
            for (int pp = 0; pp < 10; ++pp) { ofs[pp] = o; curs[pp] = o; o += cnt[pp]; }
            ofs[10] = o;
        }
        __syncthreads();
        if (havep) {
            int slot = atomicAdd(&curs[p], 1);
            pairbuf[slot] = pd;
        }
        __syncthreads();

        // phase B: uniform-p bucket loops; 8 half-wave slices stride pairs
        #pragma unroll
        for (int pp = 0; pp < 10; ++pp) {
            const int e1 = ofs[pp + 1];
            for (int qq = ofs[pp] + slice; qq < e1; qq += 8) {
                float4 v = pairbuf[qq];          // broadcast (2 addrs/wave)
                float x  = fmaf(v.y, szv, fmaf(v.x, czv, 0.5f));  // 0.5*(1+cos(th-z))
                float x2 = x * x, x4 = x2 * x2, x8 = x4 * x4, x16 = x8 * x8;
                float f1 = x16 * x16;            // x^32
                float e  = v.w - shfa;
                float f2 = __expf(-8.0f * e * e);
                a[pp] = fmaf(v.z * f2, f1, a[pp]);
            }
        }
        __syncthreads();   // protect pairbuf before next chunk
    }

    #pragma unroll
    for (int p = 0; p < 10; ++p) ang_m[slice][p * 32 + t] = a[p];
    __syncthreads();

    // ---- merge + store 384 f32 features ----
    const size_t outb = (size_t)bid * NFEAT;
    for (int f = tid; f < NFEAT; f += 256) {
        float v;
        if (f < 64) {
            v = rad_m[0][f] + rad_m[1][f] + rad_m[2][f] + rad_m[3][f];
        } else {
            const int g = f - 64;
            v = ((ang_m[0][g] + ang_m[1][g]) + (ang_m[2][g] + ang_m[3][g]))
              + ((ang_m[4][g] + ang_m[5][g]) + (ang_m[6][g] + ang_m[7][g]));
        }
        out[outb + f] = v;
    }
}

extern "C" void kernel_launch(void* const* d_in, const int* in_sizes, int n_in,
                              void* d_out, int out_size, void* d_ws, size_t ws_size,
                              hipStream_t stream) {
    if (n_in < 2) return;
    // Coordinates buffer has 3x the elements of species; pick by size so input
    // ORDER cannot break us.
    const void* coords;
    const void* species;
    if (in_sizes[0] >= in_sizes[1]) { coords = d_in[0]; species = d_in[1]; }
    else                            { coords = d_in[1]; species = d_in[0]; }
    float* out = (float*)d_out;
    AEVComputer_2156073583107_kernel<<<NMOL * A_ATOMS, 256, 0, stream>>>(coords, species, out);
}